// Round 9
// baseline (165.399 us; speedup 1.0000x reference)
//
#include <hip/hip_runtime.h>
#include <cmath>

// SSIM stability loss: 1 - mean(SSIM(x,y)), 11x11 Gaussian (sigma=1.5), zero SAME
// padding, fp32, 32 x 1 x 512 x 512.
//
// R8 (60 us kernel): 42 H-rows streamed through an 11-row LDS chunk of v4f
// (x0,y0,x1,y1) units; 11-tap window read as 6 ALIGNED ds_read_b128 with the
// lane's alignment parity folded into a 12-tap weight vector; packed v2f math;
// 11-deep circular register history for the vertical conv; single dispatch,
// fp64 atomic finish. VALU 42% + LDS ~35% and near-serial (occupancy 20%,
// ~1.6 waves/SIMD): the pipes don't overlap for lack of independent waves.
//
// R8 -> R9: column-split to 128-thread blocks (2 waves), 128 cols x 32 rows,
// grid 2048 blocks (8/CU offered; LDS 12.7 KB allows 12/CU). Work is ~equal
// (col-halo fetch 1.0625x -> 1.125x only; per-pixel H/V/LDS identical), so
// this isolates "more independent blocks -> VALU/LDS overlap" from R5's
// confounded attempt (+24% work).

#define IMG   512
#define BCOLS 128         // output columns per block (= threads)
#define BROWS 32
#define NCHUNK 4          // ceil(42/11)
#define CHR   11          // rows per LDS chunk (== history depth)
#define LCOLS 144         // staged cols per row (covers c0-8 .. c0+135)
#define LUNITS 36         // float4 units per staged row
#define NUNITS (CHR * LUNITS)   // 396
#define NBLOCKS 2048
#define NPIX  8388608.0

typedef float v2f __attribute__((ext_vector_type(2)));
typedef float v4f __attribute__((ext_vector_type(4)));

struct GaussW { float w[11]; };

__global__ __launch_bounds__(128)
void ssim_stream_kernel(const float* __restrict__ x, const float* __restrict__ y,
                        double* __restrict__ acc_ws, unsigned long long* __restrict__ ctr,
                        float* __restrict__ out, GaussW gw) {
    // tile4[s][u] = LDS cols (2u, 2u+1) packed as (x0, y0, x1, y1); 16-B units
    __shared__ v4f tile4[CHR][LCOLS / 2];   // 11 * 72 * 16 = 12672 B
    __shared__ float wavesum[2];

    const int tid = threadIdx.x;
    const int c0 = blockIdx.x * BCOLS;
    const int r0 = blockIdx.y * BROWS;
    const size_t img_off = (size_t)blockIdx.z * (IMG * IMG);
    const float* __restrict__ xb = x + img_off;
    const float* __restrict__ yb = y + img_off;

    const int ci = tid;                 // output column; taps at LDS cols ci+3..ci+13
    const int ub = (ci + 3) >> 1;       // v4f unit of aligned window base
    const int p  = (ci + 3) & 1;        // parity: tap k sits at window pos p+k

    // 12-tap per-lane weight vector: window pos m covers LDS col 2*ub + m;
    // logical tap k = m - p, so wv2[m] = w[m-p] (0 outside [0,10]).
    v2f wv2[12];
    #pragma unroll
    for (int m = 0; m < 12; ++m) {
        float lo = (m <= 10) ? gw.w[m] : 0.f;       // p == 0
        float hi = (m >= 1) ? gw.w[m - 1] : 0.f;    // p == 1
        float wm = p ? hi : lo;
        wv2[m][0] = wm; wv2[m][1] = wm;
    }
    v2f wp[11];                          // vertical weights (parity-free)
    #pragma unroll
    for (int k = 0; k < 11; ++k) { wp[k][0] = gw.w[k]; wp[k][1] = gw.w[k]; }

    float4 sxr[4], syr[4];   // staged regs for next chunk (4 iters x 128 thr >= 396)

    auto load_chunk = [&](int c) {
        #pragma unroll
        for (int it = 0; it < 4; ++it) {
            int idx = tid + it * 128;
            int row = idx / LUNITS;
            int u   = idx - row * LUNITS;
            int gr = r0 - 5 + c * CHR + row;       // global image row
            int gc = c0 - 8 + u * 4;               // global col of float4 (16B aligned)
            float4 vx = make_float4(0.f, 0.f, 0.f, 0.f);
            float4 vy = vx;
            if (idx < NUNITS && (unsigned)gr < IMG && (unsigned)gc < IMG) {
                const float* px = xb + (size_t)gr * IMG + gc;
                const float* py = yb + (size_t)gr * IMG + gc;
                vx = *(const float4*)px;
                vy = *(const float4*)py;
            }
            sxr[it] = vx; syr[it] = vy;
        }
    };
    auto store_chunk = [&]() {
        #pragma unroll
        for (int it = 0; it < 4; ++it) {
            int idx = tid + it * 128;
            if (idx < NUNITS) {
                int row = idx / LUNITS;
                int u   = idx - row * LUNITS;
                tile4[row][u * 2]     = (v4f){sxr[it].x, syr[it].x, sxr[it].y, syr[it].y};
                tile4[row][u * 2 + 1] = (v4f){sxr[it].z, syr[it].z, sxr[it].w, syr[it].w};
            }
        }
    };

    v2f hist01[11];    // (hx, hy)
    v2f hist23[11];    // (hxx, hyy)
    float hist4[11];   // hxy
    float lsum = 0.f;
    const float C1 = 1e-4f, C2 = 9e-4f;

    load_chunk(0);
    store_chunk();
    __syncthreads();

    #pragma unroll 1
    for (int c = 0; c < NCHUNK; ++c) {      // 4 chunks x 11 rows = 44 >= 42
        if (c < NCHUNK - 1) load_chunk(c + 1);  // global loads overlap chunk-c compute

        #pragma unroll
        for (int s = 0; s < CHR; ++s) {     // H-row m = 11c + s; hist slot = s
            if (!(c == NCHUNK - 1 && s >= 9)) {   // m < 42 (wave-uniform guard)
                // --- horizontal conv: 6 aligned b128 window loads, 12 taps ---
                v4f w6[6];
                #pragma unroll
                for (int i = 0; i < 6; ++i) w6[i] = tile4[s][ub + i];
                v2f h01 = (v2f){0.f, 0.f};
                v2f h23 = (v2f){0.f, 0.f};
                float h4 = 0.f;
                #pragma unroll
                for (int m = 0; m < 12; ++m) {
                    v2f t = (m & 1) ? w6[m >> 1].zw : w6[m >> 1].xy;
                    v2f tw = wv2[m] * t;                          // pk_mul
                    h01 += tw;                                    // pk_add
                    h23 = __builtin_elementwise_fma(tw, t, h23);  // pk_fma
                    h4 = fmaf(tw[0], t[1], h4);                   // w*x*y
                }
                hist01[s] = h01; hist23[s] = h23; hist4[s] = h4;

                // --- output row (11c + s - 10) completes now ---
                if (c > 0 || s == 10) {
                    v2f a01 = (v2f){0.f, 0.f};
                    v2f a23 = (v2f){0.f, 0.f};
                    float a4 = 0.f;
                    #pragma unroll
                    for (int j = 0; j < 11; ++j) {
                        const int sl = (s + 1 + j) % 11;   // static per (s,j)
                        a01 = __builtin_elementwise_fma(wp[j], hist01[sl], a01);
                        a23 = __builtin_elementwise_fma(wp[j], hist23[sl], a23);
                        a4 = fmaf(wp[j][0], hist4[sl], a4);
                    }
                    float mx = a01[0], my = a01[1];
                    float mxx = mx * mx, myy = my * my, mxy = mx * my;
                    float sxx = a23[0] - mxx, syy = a23[1] - myy, sxy = a4 - mxy;
                    float num = (2.f * mxy + C1) * (2.f * sxy + C2);
                    float den = (mxx + myy + C1) * (sxx + syy + C2);
                    lsum += num * __builtin_amdgcn_rcpf(den);
                }
            }
        }

        __syncthreads();                    // everyone done reading tile
        if (c < NCHUNK - 1) { store_chunk(); __syncthreads(); }
    }

    // ---- reduction: wave shuffle -> LDS -> block partial -> fp64 atomic ----
    #pragma unroll
    for (int off = 32; off > 0; off >>= 1)
        lsum += __shfl_down(lsum, off, 64);
    if ((tid & 63) == 0) wavesum[tid >> 6] = lsum;
    __syncthreads();
    if (tid == 0) {
        float bs = wavesum[0] + wavesum[1];
        atomicAdd(acc_ws, (double)bs);
        __threadfence();
        unsigned long long old = atomicAdd(ctr, 1ull);
        if (old == (unsigned long long)(NBLOCKS - 1)) {
            __threadfence();
            double total = atomicAdd(acc_ws, 0.0);   // atomic RMW sees all prior adds
            out[0] = (float)(1.0 - total / NPIX);
        }
    }
}

extern "C" void kernel_launch(void* const* d_in, const int* in_sizes, int n_in,
                              void* d_out, int out_size, void* d_ws, size_t ws_size,
                              hipStream_t stream) {
    const float* x = (const float*)d_in[0];   // heatmap_clean
    const float* y = (const float*)d_in[1];   // heatmap_adv
    float* out = (float*)d_out;
    double* acc = (double*)d_ws;
    unsigned long long* ctr = (unsigned long long*)((char*)d_ws + 8);

    // zero the 16B of accumulator+counter state (capture-safe async memset)
    hipMemsetAsync(d_ws, 0, 16, stream);

    GaussW gw;
    double g[11], s = 0.0;
    for (int i = 0; i < 11; ++i) { double d = i - 5; g[i] = exp(-(d * d) / 4.5); s += g[i]; }
    for (int i = 0; i < 11; ++i) gw.w[i] = (float)(g[i] / s);

    dim3 grid(IMG / BCOLS, IMG / BROWS, 32);   // (4, 16, 32) = 2048 blocks
    ssim_stream_kernel<<<grid, 128, 0, stream>>>(x, y, acc, ctr, out, gw);
}

// Round 10
// 130.826 us; speedup vs baseline: 1.2643x; 1.2643x over previous
//
#include <hip/hip_runtime.h>
#include <cmath>

// SSIM stability loss: 1 - mean(SSIM(x,y)), 11x11 Gaussian (sigma=1.5), zero SAME
// padding, fp32, 32 x 1 x 512 x 512.
//
// R8 structure (best: 60 us kernel): 256 threads = 256 cols x 32-row band,
// 42 H-rows streamed through an 11-row LDS chunk of v4f (x0,y0,x1,y1) units;
// 11-tap window read as 6 ALIGNED ds_read_b128 with the lane's alignment
// parity folded into a 12-tap weight vector; 11-deep circular register history
// for the vertical conv; single dispatch, fp64 atomic finish.
//
// R9 -> R10: grid/block reshaping is a dead end (R5/R6/R9 all failed to move
// occupancy). R8's lesson: dur tracks serial-chain instruction count. Measured
// VALU issue (60K cyc/SIMD) is 2.2x the hand count for truly-packed math
// (~27K) -> the v2f __builtin_elementwise_fma path is suspected of lowering
// partly to scalar v_fma_f32. This round forces v_pk_mul_f32 / v_pk_add_f32 /
// v_pk_fma_f32 via inline asm (VOP3P; v2f = even-aligned VGPR pair) in the
// hot H and V loops. Everything else identical to R8.

#define IMG   512
#define BROWS 32
#define NCHUNK 4          // ceil(42/11)
#define CHR   11          // rows per LDS chunk (== history depth)
#define LCOLS 272         // staged cols per row (covers c0-8 .. c0+263)
#define LUNITS 68         // float4 units per staged row
#define NUNITS (CHR * LUNITS)   // 748
#define NBLOCKS 1024
#define NPIX  8388608.0

typedef float v2f __attribute__((ext_vector_type(2)));
typedef float v4f __attribute__((ext_vector_type(4)));

__device__ __forceinline__ v2f pk_mul(v2f a, v2f b) {
    v2f d;
    asm("v_pk_mul_f32 %0, %1, %2" : "=v"(d) : "v"(a), "v"(b));
    return d;
}
__device__ __forceinline__ v2f pk_add(v2f a, v2f b) {
    v2f d;
    asm("v_pk_add_f32 %0, %1, %2" : "=v"(d) : "v"(a), "v"(b));
    return d;
}
__device__ __forceinline__ v2f pk_fma(v2f a, v2f b, v2f c) {
    v2f d;
    asm("v_pk_fma_f32 %0, %1, %2, %3" : "=v"(d) : "v"(a), "v"(b), "v"(c));
    return d;
}

struct GaussW { float w[11]; };

__global__ __launch_bounds__(256)
void ssim_stream_kernel(const float* __restrict__ x, const float* __restrict__ y,
                        double* __restrict__ acc_ws, unsigned long long* __restrict__ ctr,
                        float* __restrict__ out, GaussW gw) {
    // tile4[s][u] = LDS cols (2u, 2u+1) packed as (x0, y0, x1, y1); 16-B units
    __shared__ v4f tile4[CHR][LCOLS / 2];   // 11 * 136 * 16 = 23936 B
    __shared__ float wavesum[4];

    const int tid = threadIdx.x;
    const int c0 = blockIdx.x * 256;
    const int r0 = blockIdx.y * BROWS;
    const size_t img_off = (size_t)blockIdx.z * (IMG * IMG);
    const float* __restrict__ xb = x + img_off;
    const float* __restrict__ yb = y + img_off;

    const int ci = tid;                 // output column; taps at LDS cols ci+3..ci+13
    const int ub = (ci + 3) >> 1;       // v4f unit of aligned window base
    const int p  = (ci + 3) & 1;        // parity: tap k sits at window pos p+k

    // 12-tap per-lane weight vector: window pos m covers LDS col 2*ub + m;
    // logical tap k = m - p, so wv2[m] = w[m-p] (0 outside [0,10]).
    v2f wv2[12];
    #pragma unroll
    for (int m = 0; m < 12; ++m) {
        float lo = (m <= 10) ? gw.w[m] : 0.f;       // p == 0
        float hi = (m >= 1) ? gw.w[m - 1] : 0.f;    // p == 1
        float wm = p ? hi : lo;
        wv2[m][0] = wm; wv2[m][1] = wm;
    }
    v2f wp[11];                          // vertical weights (parity-free)
    #pragma unroll
    for (int k = 0; k < 11; ++k) { wp[k][0] = gw.w[k]; wp[k][1] = gw.w[k]; }

    float4 sxr[3], syr[3];   // staged regs for next chunk (3 iters x 256 thr >= 748)

    auto load_chunk = [&](int c) {
        #pragma unroll
        for (int it = 0; it < 3; ++it) {
            int idx = tid + it * 256;
            int row = idx / LUNITS;
            int u   = idx - row * LUNITS;
            int gr = r0 - 5 + c * CHR + row;       // global image row
            int gc = c0 - 8 + u * 4;               // global col of float4 (16B aligned)
            float4 vx = make_float4(0.f, 0.f, 0.f, 0.f);
            float4 vy = vx;
            if (idx < NUNITS && (unsigned)gr < IMG && (unsigned)gc < IMG) {
                const float* px = xb + (size_t)gr * IMG + gc;
                const float* py = yb + (size_t)gr * IMG + gc;
                vx = *(const float4*)px;
                vy = *(const float4*)py;
            }
            sxr[it] = vx; syr[it] = vy;
        }
    };
    auto store_chunk = [&]() {
        #pragma unroll
        for (int it = 0; it < 3; ++it) {
            int idx = tid + it * 256;
            if (idx < NUNITS) {
                int row = idx / LUNITS;
                int u   = idx - row * LUNITS;
                tile4[row][u * 2]     = (v4f){sxr[it].x, syr[it].x, sxr[it].y, syr[it].y};
                tile4[row][u * 2 + 1] = (v4f){sxr[it].z, syr[it].z, sxr[it].w, syr[it].w};
            }
        }
    };

    v2f hist01[11];    // (hx, hy)
    v2f hist23[11];    // (hxx, hyy)
    float hist4[11];   // hxy
    float lsum = 0.f;
    const float C1 = 1e-4f, C2 = 9e-4f;

    load_chunk(0);
    store_chunk();
    __syncthreads();

    #pragma unroll 1
    for (int c = 0; c < NCHUNK; ++c) {      // 4 chunks x 11 rows = 44 >= 42
        if (c < NCHUNK - 1) load_chunk(c + 1);  // global loads overlap chunk-c compute

        #pragma unroll
        for (int s = 0; s < CHR; ++s) {     // H-row m = 11c + s; hist slot = s
            if (!(c == NCHUNK - 1 && s >= 9)) {   // m < 42 (wave-uniform guard)
                // --- horizontal conv: 6 aligned b128 window loads, 12 taps ---
                v4f w6[6];
                #pragma unroll
                for (int i = 0; i < 6; ++i) w6[i] = tile4[s][ub + i];
                v2f h01 = (v2f){0.f, 0.f};
                v2f h23 = (v2f){0.f, 0.f};
                float h4 = 0.f;
                #pragma unroll
                for (int m = 0; m < 12; ++m) {
                    v2f t = (m & 1) ? w6[m >> 1].zw : w6[m >> 1].xy;
                    v2f tw = pk_mul(wv2[m], t);       // v_pk_mul_f32
                    h01 = pk_add(h01, tw);            // v_pk_add_f32
                    h23 = pk_fma(tw, t, h23);         // v_pk_fma_f32
                    h4 = fmaf(tw[0], t[1], h4);       // w*x*y (scalar)
                }
                hist01[s] = h01; hist23[s] = h23; hist4[s] = h4;

                // --- output row (11c + s - 10) completes now ---
                if (c > 0 || s == 10) {
                    v2f a01 = (v2f){0.f, 0.f};
                    v2f a23 = (v2f){0.f, 0.f};
                    float a4 = 0.f;
                    #pragma unroll
                    for (int j = 0; j < 11; ++j) {
                        const int sl = (s + 1 + j) % 11;   // static per (s,j)
                        a01 = pk_fma(wp[j], hist01[sl], a01);
                        a23 = pk_fma(wp[j], hist23[sl], a23);
                        a4 = fmaf(wp[j][0], hist4[sl], a4);
                    }
                    float mx = a01[0], my = a01[1];
                    float mxx = mx * mx, myy = my * my, mxy = mx * my;
                    float sxx = a23[0] - mxx, syy = a23[1] - myy, sxy = a4 - mxy;
                    float num = (2.f * mxy + C1) * (2.f * sxy + C2);
                    float den = (mxx + myy + C1) * (sxx + syy + C2);
                    lsum += num * __builtin_amdgcn_rcpf(den);
                }
            }
        }

        __syncthreads();                    // everyone done reading tile
        if (c < NCHUNK - 1) { store_chunk(); __syncthreads(); }
    }

    // ---- reduction: wave shuffle -> LDS -> block partial -> fp64 atomic ----
    #pragma unroll
    for (int off = 32; off > 0; off >>= 1)
        lsum += __shfl_down(lsum, off, 64);
    if ((tid & 63) == 0) wavesum[tid >> 6] = lsum;
    __syncthreads();
    if (tid == 0) {
        float bs = wavesum[0] + wavesum[1] + wavesum[2] + wavesum[3];
        atomicAdd(acc_ws, (double)bs);
        __threadfence();
        unsigned long long old = atomicAdd(ctr, 1ull);
        if (old == (unsigned long long)(NBLOCKS - 1)) {
            __threadfence();
            double total = atomicAdd(acc_ws, 0.0);   // atomic RMW sees all prior adds
            out[0] = (float)(1.0 - total / NPIX);
        }
    }
}

extern "C" void kernel_launch(void* const* d_in, const int* in_sizes, int n_in,
                              void* d_out, int out_size, void* d_ws, size_t ws_size,
                              hipStream_t stream) {
    const float* x = (const float*)d_in[0];   // heatmap_clean
    const float* y = (const float*)d_in[1];   // heatmap_adv
    float* out = (float*)d_out;
    double* acc = (double*)d_ws;
    unsigned long long* ctr = (unsigned long long*)((char*)d_ws + 8);

    // zero the 16B of accumulator+counter state (capture-safe async memset)
    hipMemsetAsync(d_ws, 0, 16, stream);

    GaussW gw;
    double g[11], s = 0.0;
    for (int i = 0; i < 11; ++i) { double d = i - 5; g[i] = exp(-(d * d) / 4.5); s += g[i]; }
    for (int i = 0; i < 11; ++i) gw.w[i] = (float)(g[i] / s);

    dim3 grid(2, IMG / BROWS, 32);   // (2, 16, 32) = 1024 blocks
    ssim_stream_kernel<<<grid, 256, 0, stream>>>(x, y, acc, ctr, out, gw);
}

// Round 11
// 126.904 us; speedup vs baseline: 1.3033x; 1.0309x over previous
//
#include <hip/hip_runtime.h>
#include <cmath>

// SSIM stability loss: 1 - mean(SSIM(x,y)), 11x11 Gaussian (sigma=1.5), zero SAME
// padding, fp32, 32 x 1 x 512 x 512.
//
// R8 structure (best: 60 us kernel): 256 threads = 256 cols x band,
// H-rows streamed through an 11-row LDS chunk of v4f (x0,y0,x1,y1) units;
// 11-tap window read as 6 ALIGNED ds_read_b128 with the lane's alignment
// parity folded into a 12-tap weight vector; packed v2f builtins (confirmed
// by R10 to already lower to v_pk_*; forcing asm regressed); 11-deep circular
// register history for the vertical conv; single dispatch, fp64 atomic finish.
//
// R10 -> R11: VALUBusy is overstated ~2x by the gfx94x fallback formula
// (SIMD-16 assumption); true pipes are ~20% busy -> latency-bound, and the
// only lever that has ever moved dur is serial-chain instructions per pixel.
// BROWS 32 -> 64 cuts the row-halo factor 1.3125x -> 1.156x: -12% H-VALU,
// -12% LDS reads, -12% staging per pixel, barriers/px halved. LDS unchanged
// (24 KB chunk), NCHUNK 4 -> 7, grid 512 blocks.

#define IMG   512
#define BROWS 64
#define NHROW (BROWS + 10)   // 74 H-rows per band
#define NCHUNK 7             // ceil(74/11)
#define CHR   11             // rows per LDS chunk (== history depth)
#define LCOLS 272            // staged cols per row (covers c0-8 .. c0+263)
#define LUNITS 68            // float4 units per staged row
#define NUNITS (CHR * LUNITS)   // 748
#define NBLOCKS 512
#define NPIX  8388608.0

typedef float v2f __attribute__((ext_vector_type(2)));
typedef float v4f __attribute__((ext_vector_type(4)));

struct GaussW { float w[11]; };

__global__ __launch_bounds__(256)
void ssim_stream_kernel(const float* __restrict__ x, const float* __restrict__ y,
                        double* __restrict__ acc_ws, unsigned long long* __restrict__ ctr,
                        float* __restrict__ out, GaussW gw) {
    // tile4[s][u] = LDS cols (2u, 2u+1) packed as (x0, y0, x1, y1); 16-B units
    __shared__ v4f tile4[CHR][LCOLS / 2];   // 11 * 136 * 16 = 23936 B
    __shared__ float wavesum[4];

    const int tid = threadIdx.x;
    const int c0 = blockIdx.x * 256;
    const int r0 = blockIdx.y * BROWS;
    const size_t img_off = (size_t)blockIdx.z * (IMG * IMG);
    const float* __restrict__ xb = x + img_off;
    const float* __restrict__ yb = y + img_off;

    const int ci = tid;                 // output column; taps at LDS cols ci+3..ci+13
    const int ub = (ci + 3) >> 1;       // v4f unit of aligned window base
    const int p  = (ci + 3) & 1;        // parity: tap k sits at window pos p+k

    // 12-tap per-lane weight vector: window pos m covers LDS col 2*ub + m;
    // logical tap k = m - p, so wv2[m] = w[m-p] (0 outside [0,10]).
    v2f wv2[12];
    #pragma unroll
    for (int m = 0; m < 12; ++m) {
        float lo = (m <= 10) ? gw.w[m] : 0.f;       // p == 0
        float hi = (m >= 1) ? gw.w[m - 1] : 0.f;    // p == 1
        float wm = p ? hi : lo;
        wv2[m][0] = wm; wv2[m][1] = wm;
    }
    v2f wp[11];                          // vertical weights (parity-free)
    #pragma unroll
    for (int k = 0; k < 11; ++k) { wp[k][0] = gw.w[k]; wp[k][1] = gw.w[k]; }

    float4 sxr[3], syr[3];   // staged regs for next chunk (3 iters x 256 thr >= 748)

    auto load_chunk = [&](int c) {
        #pragma unroll
        for (int it = 0; it < 3; ++it) {
            int idx = tid + it * 256;
            int row = idx / LUNITS;
            int u   = idx - row * LUNITS;
            int gr = r0 - 5 + c * CHR + row;       // global image row
            int gc = c0 - 8 + u * 4;               // global col of float4 (16B aligned)
            float4 vx = make_float4(0.f, 0.f, 0.f, 0.f);
            float4 vy = vx;
            if (idx < NUNITS && (unsigned)gr < IMG && (unsigned)gc < IMG) {
                const float* px = xb + (size_t)gr * IMG + gc;
                const float* py = yb + (size_t)gr * IMG + gc;
                vx = *(const float4*)px;
                vy = *(const float4*)py;
            }
            sxr[it] = vx; syr[it] = vy;
        }
    };
    auto store_chunk = [&]() {
        #pragma unroll
        for (int it = 0; it < 3; ++it) {
            int idx = tid + it * 256;
            if (idx < NUNITS) {
                int row = idx / LUNITS;
                int u   = idx - row * LUNITS;
                tile4[row][u * 2]     = (v4f){sxr[it].x, syr[it].x, sxr[it].y, syr[it].y};
                tile4[row][u * 2 + 1] = (v4f){sxr[it].z, syr[it].z, sxr[it].w, syr[it].w};
            }
        }
    };

    v2f hist01[11];    // (hx, hy)
    v2f hist23[11];    // (hxx, hyy)
    float hist4[11];   // hxy
    float lsum = 0.f;
    const float C1 = 1e-4f, C2 = 9e-4f;

    load_chunk(0);
    store_chunk();
    __syncthreads();

    #pragma unroll 1
    for (int c = 0; c < NCHUNK; ++c) {      // 7 chunks x 11 rows = 77 >= 74
        if (c < NCHUNK - 1) load_chunk(c + 1);  // global loads overlap chunk-c compute

        #pragma unroll
        for (int s = 0; s < CHR; ++s) {     // H-row m = 11c + s; hist slot = s
            if (!(c == NCHUNK - 1 && s >= 8)) {   // m < 74 (wave-uniform guard)
                // --- horizontal conv: 6 aligned b128 window loads, 12 taps ---
                v4f w6[6];
                #pragma unroll
                for (int i = 0; i < 6; ++i) w6[i] = tile4[s][ub + i];
                v2f h01 = (v2f){0.f, 0.f};
                v2f h23 = (v2f){0.f, 0.f};
                float h4 = 0.f;
                #pragma unroll
                for (int m = 0; m < 12; ++m) {
                    v2f t = (m & 1) ? w6[m >> 1].zw : w6[m >> 1].xy;
                    v2f tw = wv2[m] * t;                          // v_pk_mul_f32
                    h01 += tw;                                    // v_pk_add_f32
                    h23 = __builtin_elementwise_fma(tw, t, h23);  // v_pk_fma_f32
                    h4 = fmaf(tw[0], t[1], h4);                   // w*x*y (scalar)
                }
                hist01[s] = h01; hist23[s] = h23; hist4[s] = h4;

                // --- output row (11c + s - 10) completes now ---
                if (c > 0 || s == 10) {
                    v2f a01 = (v2f){0.f, 0.f};
                    v2f a23 = (v2f){0.f, 0.f};
                    float a4 = 0.f;
                    #pragma unroll
                    for (int j = 0; j < 11; ++j) {
                        const int sl = (s + 1 + j) % 11;   // static per (s,j)
                        a01 = __builtin_elementwise_fma(wp[j], hist01[sl], a01);
                        a23 = __builtin_elementwise_fma(wp[j], hist23[sl], a23);
                        a4 = fmaf(wp[j][0], hist4[sl], a4);
                    }
                    float mx = a01[0], my = a01[1];
                    float mxx = mx * mx, myy = my * my, mxy = mx * my;
                    float sxx = a23[0] - mxx, syy = a23[1] - myy, sxy = a4 - mxy;
                    float num = (2.f * mxy + C1) * (2.f * sxy + C2);
                    float den = (mxx + myy + C1) * (sxx + syy + C2);
                    lsum += num * __builtin_amdgcn_rcpf(den);
                }
            }
        }

        __syncthreads();                    // everyone done reading tile
        if (c < NCHUNK - 1) { store_chunk(); __syncthreads(); }
    }

    // ---- reduction: wave shuffle -> LDS -> block partial -> fp64 atomic ----
    #pragma unroll
    for (int off = 32; off > 0; off >>= 1)
        lsum += __shfl_down(lsum, off, 64);
    if ((tid & 63) == 0) wavesum[tid >> 6] = lsum;
    __syncthreads();
    if (tid == 0) {
        float bs = wavesum[0] + wavesum[1] + wavesum[2] + wavesum[3];
        atomicAdd(acc_ws, (double)bs);
        __threadfence();
        unsigned long long old = atomicAdd(ctr, 1ull);
        if (old == (unsigned long long)(NBLOCKS - 1)) {
            __threadfence();
            double total = atomicAdd(acc_ws, 0.0);   // atomic RMW sees all prior adds
            out[0] = (float)(1.0 - total / NPIX);
        }
    }
}

extern "C" void kernel_launch(void* const* d_in, const int* in_sizes, int n_in,
                              void* d_out, int out_size, void* d_ws, size_t ws_size,
                              hipStream_t stream) {
    const float* x = (const float*)d_in[0];   // heatmap_clean
    const float* y = (const float*)d_in[1];   // heatmap_adv
    float* out = (float*)d_out;
    double* acc = (double*)d_ws;
    unsigned long long* ctr = (unsigned long long*)((char*)d_ws + 8);

    // zero the 16B of accumulator+counter state (capture-safe async memset)
    hipMemsetAsync(d_ws, 0, 16, stream);

    GaussW gw;
    double g[11], s = 0.0;
    for (int i = 0; i < 11; ++i) { double d = i - 5; g[i] = exp(-(d * d) / 4.5); s += g[i]; }
    for (int i = 0; i < 11; ++i) gw.w[i] = (float)(g[i] / s);

    dim3 grid(2, IMG / BROWS, 32);   // (2, 8, 32) = 512 blocks
    ssim_stream_kernel<<<grid, 256, 0, stream>>>(x, y, acc, ctr, out, gw);
}

// Round 12
// 126.174 us; speedup vs baseline: 1.3109x; 1.0058x over previous
//
#include <hip/hip_runtime.h>
#include <cmath>

// SSIM stability loss: 1 - mean(SSIM(x,y)), 11x11 Gaussian (sigma=1.5), zero SAME
// padding, fp32, 32 x 1 x 512 x 512.
//
// Structure (R8 lineage, best-measured): 256 threads = 256 cols x BROWS band,
// H-rows streamed through an 11-row LDS chunk of v4f (x0,y0,x1,y1) units;
// 11-tap window read as 6 ALIGNED ds_read_b128 with the lane's alignment
// parity folded into a 12-tap weight vector; packed v2f builtins (R10: these
// already lower to v_pk_*; forcing asm regressed); 11-deep circular register
// history for the vertical conv; single dispatch, fp64 atomic finish.
//
// R11 -> R12: the one lever that reliably moves dur is serial-chain work per
// pixel (R11: halo 1.31->1.16 gave -22% dur; occupancy is immovable and
// irrelevant in this regime -- falsified 3x). One more step: BROWS 64 -> 128,
// halo 1.156 -> 1.078 (-7% H-VALU and LDS reads/px, -5% fetch, prologues
// halved). Grid 256 blocks = exactly 1/CU.

#define IMG   512
#define BROWS 128
#define NHROW (BROWS + 10)   // 138 H-rows per band
#define NCHUNK 13            // ceil(138/11)
#define CHR   11             // rows per LDS chunk (== history depth)
#define LCOLS 272            // staged cols per row (covers c0-8 .. c0+263)
#define LUNITS 68            // float4 units per staged row
#define NUNITS (CHR * LUNITS)   // 748
#define NBLOCKS 256
#define NPIX  8388608.0

typedef float v2f __attribute__((ext_vector_type(2)));
typedef float v4f __attribute__((ext_vector_type(4)));

struct GaussW { float w[11]; };

__global__ __launch_bounds__(256)
void ssim_stream_kernel(const float* __restrict__ x, const float* __restrict__ y,
                        double* __restrict__ acc_ws, unsigned long long* __restrict__ ctr,
                        float* __restrict__ out, GaussW gw) {
    // tile4[s][u] = LDS cols (2u, 2u+1) packed as (x0, y0, x1, y1); 16-B units
    __shared__ v4f tile4[CHR][LCOLS / 2];   // 11 * 136 * 16 = 23936 B
    __shared__ float wavesum[4];

    const int tid = threadIdx.x;
    const int c0 = blockIdx.x * 256;
    const int r0 = blockIdx.y * BROWS;
    const size_t img_off = (size_t)blockIdx.z * (IMG * IMG);
    const float* __restrict__ xb = x + img_off;
    const float* __restrict__ yb = y + img_off;

    const int ci = tid;                 // output column; taps at LDS cols ci+3..ci+13
    const int ub = (ci + 3) >> 1;       // v4f unit of aligned window base
    const int p  = (ci + 3) & 1;        // parity: tap k sits at window pos p+k

    // 12-tap per-lane weight vector: window pos m covers LDS col 2*ub + m;
    // logical tap k = m - p, so wv2[m] = w[m-p] (0 outside [0,10]).
    v2f wv2[12];
    #pragma unroll
    for (int m = 0; m < 12; ++m) {
        float lo = (m <= 10) ? gw.w[m] : 0.f;       // p == 0
        float hi = (m >= 1) ? gw.w[m - 1] : 0.f;    // p == 1
        float wm = p ? hi : lo;
        wv2[m][0] = wm; wv2[m][1] = wm;
    }
    v2f wp[11];                          // vertical weights (parity-free)
    #pragma unroll
    for (int k = 0; k < 11; ++k) { wp[k][0] = gw.w[k]; wp[k][1] = gw.w[k]; }

    float4 sxr[3], syr[3];   // staged regs for next chunk (3 iters x 256 thr >= 748)

    auto load_chunk = [&](int c) {
        #pragma unroll
        for (int it = 0; it < 3; ++it) {
            int idx = tid + it * 256;
            int row = idx / LUNITS;
            int u   = idx - row * LUNITS;
            int gr = r0 - 5 + c * CHR + row;       // global image row
            int gc = c0 - 8 + u * 4;               // global col of float4 (16B aligned)
            float4 vx = make_float4(0.f, 0.f, 0.f, 0.f);
            float4 vy = vx;
            if (idx < NUNITS && (unsigned)gr < IMG && (unsigned)gc < IMG) {
                const float* px = xb + (size_t)gr * IMG + gc;
                const float* py = yb + (size_t)gr * IMG + gc;
                vx = *(const float4*)px;
                vy = *(const float4*)py;
            }
            sxr[it] = vx; syr[it] = vy;
        }
    };
    auto store_chunk = [&]() {
        #pragma unroll
        for (int it = 0; it < 3; ++it) {
            int idx = tid + it * 256;
            if (idx < NUNITS) {
                int row = idx / LUNITS;
                int u   = idx - row * LUNITS;
                tile4[row][u * 2]     = (v4f){sxr[it].x, syr[it].x, sxr[it].y, syr[it].y};
                tile4[row][u * 2 + 1] = (v4f){sxr[it].z, syr[it].z, sxr[it].w, syr[it].w};
            }
        }
    };

    v2f hist01[11];    // (hx, hy)
    v2f hist23[11];    // (hxx, hyy)
    float hist4[11];   // hxy
    float lsum = 0.f;
    const float C1 = 1e-4f, C2 = 9e-4f;

    load_chunk(0);
    store_chunk();
    __syncthreads();

    #pragma unroll 1
    for (int c = 0; c < NCHUNK; ++c) {      // 13 chunks x 11 rows = 143 >= 138
        if (c < NCHUNK - 1) load_chunk(c + 1);  // global loads overlap chunk-c compute

        #pragma unroll
        for (int s = 0; s < CHR; ++s) {     // H-row m = 11c + s; hist slot = s
            if (!(c == NCHUNK - 1 && s >= 6)) {   // m < 138 (wave-uniform guard)
                // --- horizontal conv: 6 aligned b128 window loads, 12 taps ---
                v4f w6[6];
                #pragma unroll
                for (int i = 0; i < 6; ++i) w6[i] = tile4[s][ub + i];
                v2f h01 = (v2f){0.f, 0.f};
                v2f h23 = (v2f){0.f, 0.f};
                float h4 = 0.f;
                #pragma unroll
                for (int m = 0; m < 12; ++m) {
                    v2f t = (m & 1) ? w6[m >> 1].zw : w6[m >> 1].xy;
                    v2f tw = wv2[m] * t;                          // v_pk_mul_f32
                    h01 += tw;                                    // v_pk_add_f32
                    h23 = __builtin_elementwise_fma(tw, t, h23);  // v_pk_fma_f32
                    h4 = fmaf(tw[0], t[1], h4);                   // w*x*y (scalar)
                }
                hist01[s] = h01; hist23[s] = h23; hist4[s] = h4;

                // --- output row (11c + s - 10) completes now ---
                if (c > 0 || s == 10) {
                    v2f a01 = (v2f){0.f, 0.f};
                    v2f a23 = (v2f){0.f, 0.f};
                    float a4 = 0.f;
                    #pragma unroll
                    for (int j = 0; j < 11; ++j) {
                        const int sl = (s + 1 + j) % 11;   // static per (s,j)
                        a01 = __builtin_elementwise_fma(wp[j], hist01[sl], a01);
                        a23 = __builtin_elementwise_fma(wp[j], hist23[sl], a23);
                        a4 = fmaf(wp[j][0], hist4[sl], a4);
                    }
                    float mx = a01[0], my = a01[1];
                    float mxx = mx * mx, myy = my * my, mxy = mx * my;
                    float sxx = a23[0] - mxx, syy = a23[1] - myy, sxy = a4 - mxy;
                    float num = (2.f * mxy + C1) * (2.f * sxy + C2);
                    float den = (mxx + myy + C1) * (sxx + syy + C2);
                    lsum += num * __builtin_amdgcn_rcpf(den);
                }
            }
        }

        __syncthreads();                    // everyone done reading tile
        if (c < NCHUNK - 1) { store_chunk(); __syncthreads(); }
    }

    // ---- reduction: wave shuffle -> LDS -> block partial -> fp64 atomic ----
    #pragma unroll
    for (int off = 32; off > 0; off >>= 1)
        lsum += __shfl_down(lsum, off, 64);
    if ((tid & 63) == 0) wavesum[tid >> 6] = lsum;
    __syncthreads();
    if (tid == 0) {
        float bs = wavesum[0] + wavesum[1] + wavesum[2] + wavesum[3];
        atomicAdd(acc_ws, (double)bs);
        __threadfence();
        unsigned long long old = atomicAdd(ctr, 1ull);
        if (old == (unsigned long long)(NBLOCKS - 1)) {
            __threadfence();
            double total = atomicAdd(acc_ws, 0.0);   // atomic RMW sees all prior adds
            out[0] = (float)(1.0 - total / NPIX);
        }
    }
}

extern "C" void kernel_launch(void* const* d_in, const int* in_sizes, int n_in,
                              void* d_out, int out_size, void* d_ws, size_t ws_size,
                              hipStream_t stream) {
    const float* x = (const float*)d_in[0];   // heatmap_clean
    const float* y = (const float*)d_in[1];   // heatmap_adv
    float* out = (float*)d_out;
    double* acc = (double*)d_ws;
    unsigned long long* ctr = (unsigned long long*)((char*)d_ws + 8);

    // zero the 16B of accumulator+counter state (capture-safe async memset)
    hipMemsetAsync(d_ws, 0, 16, stream);

    GaussW gw;
    double g[11], s = 0.0;
    for (int i = 0; i < 11; ++i) { double d = i - 5; g[i] = exp(-(d * d) / 4.5); s += g[i]; }
    for (int i = 0; i < 11; ++i) gw.w[i] = (float)(g[i] / s);

    dim3 grid(2, IMG / BROWS, 32);   // (2, 4, 32) = 256 blocks = 1 per CU
    ssim_stream_kernel<<<grid, 256, 0, stream>>>(x, y, acc, ctr, out, gw);
}

// Round 13
// 123.510 us; speedup vs baseline: 1.3391x; 1.0216x over previous
//
#include <hip/hip_runtime.h>
#include <cmath>

// SSIM stability loss: 1 - mean(SSIM(x,y)), 11x11 Gaussian (sigma=1.5), zero SAME
// padding, fp32, 32 x 1 x 512 x 512.
//
// R12 -> R13: 2 blocks/CU (512 blocks) is the proven overlap sweet spot (R12's
// 1/CU cost +13%); the remaining lever is serial work per pixel. This round:
// each thread computes 2 ADJACENT columns (256 threads = full 512-col width,
// no column halo; edge units statically zero). The pair's joint 13-col window
// is 7 aligned ds_read_b128 SHARED by both columns: LDS bytes 96 -> 56 B/px
// (-42%), instrs 6 -> 3.5/px. Vertical conv packs the xy channel across the
// column pair (hist4 = v2f): 33 -> 27.5 instr/px. H-conv ~flat. Same streamed
// 11-row chunk pipeline, packed v2f builtins, fp64 atomic finish.

#define IMG   512
#define BROWS 32
#define NHROW 42             // H-rows per band
#define NCHUNK 4             // 4*11 = 44 >= 42
#define CHR   11             // rows per LDS chunk (== history depth)
#define NUL   262            // LDS v4f units per row: 3 zero + 256 data + 3 zero
#define GF4   128            // global float4 per row per input (512 cols)
#define NSTAGE (CHR * GF4)   // 1408
#define NBLOCKS 512
#define NPIX  8388608.0

typedef float v2f __attribute__((ext_vector_type(2)));
typedef float v4f __attribute__((ext_vector_type(4)));

struct GaussW { float w[11]; };

__global__ __launch_bounds__(256)
void ssim_stream_kernel(const float* __restrict__ x, const float* __restrict__ y,
                        double* __restrict__ acc_ws, unsigned long long* __restrict__ ctr,
                        float* __restrict__ out, GaussW gw) {
    // tile4[s][3+u] = image cols (2u, 2u+1) as (x0,y0,x1,y1); units 0-2 and
    // 259-261 are permanent zeros (left/right SAME padding).
    __shared__ v4f tile4[CHR][NUL];     // 11 * 262 * 16 = 46112 B
    __shared__ float wavesum[4];

    const int tid = threadIdx.x;
    const int r0 = blockIdx.x * BROWS;
    const size_t img_off = (size_t)blockIdx.y * (IMG * IMG);
    const float* __restrict__ xb = x + img_off;
    const float* __restrict__ yb = y + img_off;

    // static zero halo units (written once; store_chunk never touches them)
    if (tid < 66) {
        int r = tid / 6, j = tid - 6 * r;
        int u = (j < 3) ? j : 256 + j;
        tile4[r][u] = (v4f){0.f, 0.f, 0.f, 0.f};
    }

    v2f wp[11];                          // broadcast Gaussian weights
    #pragma unroll
    for (int k = 0; k < 11; ++k) { wp[k][0] = gw.w[k]; wp[k][1] = gw.w[k]; }

    float4 sxr[6], syr[6];   // staged regs for next chunk (6 x 256 >= 1408)

    auto load_chunk = [&](int c) {
        #pragma unroll
        for (int it = 0; it < 6; ++it) {
            int idx = tid + it * 256;
            int row = idx >> 7;                   // / GF4
            int u   = idx & 127;
            int gr = r0 - 5 + c * CHR + row;
            float4 vx = make_float4(0.f, 0.f, 0.f, 0.f);
            float4 vy = vx;
            if (idx < NSTAGE && (unsigned)gr < IMG) {
                const float* px = xb + (size_t)gr * IMG + 4 * u;
                const float* py = yb + (size_t)gr * IMG + 4 * u;
                vx = *(const float4*)px;
                vy = *(const float4*)py;
            }
            sxr[it] = vx; syr[it] = vy;
        }
    };
    auto store_chunk = [&]() {
        #pragma unroll
        for (int it = 0; it < 6; ++it) {
            int idx = tid + it * 256;
            if (idx < NSTAGE) {
                int row = idx >> 7;
                int u   = idx & 127;
                tile4[row][2 * u + 3] = (v4f){sxr[it].x, syr[it].x, sxr[it].y, syr[it].y};
                tile4[row][2 * u + 4] = (v4f){sxr[it].z, syr[it].z, sxr[it].w, syr[it].w};
            }
        }
    };

    // circular register history, 2 columns per thread (A = 2t, B = 2t+1)
    v2f hist01A[11], hist01B[11];   // (hx, hy)
    v2f hist23A[11], hist23B[11];   // (hxx, hyy)
    v2f hist4[11];                  // (hxy_A, hxy_B)
    float lsum = 0.f;
    const float C1 = 1e-4f, C2 = 9e-4f;

    auto ssim1 = [&](v2f a01, v2f a23, float a4s) -> float {
        v2f mm = a01 * a01;                  // (mxx, myy)  pk_mul
        float mxy = a01[0] * a01[1];
        v2f s23 = a23 - mm;                  // (sxx, syy)  pk_sub
        float sxy = a4s - mxy;
        float num = fmaf(2.f, mxy, C1) * fmaf(2.f, sxy, C2);
        float den = (mm[0] + mm[1] + C1) * (s23[0] + s23[1] + C2);
        return num * __builtin_amdgcn_rcpf(den);
    };

    load_chunk(0);
    store_chunk();
    __syncthreads();

    #pragma unroll 1
    for (int c = 0; c < NCHUNK; ++c) {      // 4 chunks x 11 rows = 44 >= 42
        if (c < NCHUNK - 1) load_chunk(c + 1);  // global loads overlap chunk-c compute

        #pragma unroll
        for (int s = 0; s < CHR; ++s) {     // H-row m = 11c + s; hist slot = s
            if (!(c == NCHUNK - 1 && s >= 9)) {   // m < 42 (wave-uniform guard)
                // --- joint 13-col window: 7 aligned b128 loads for BOTH cols ---
                // window position m (1..12) = half (m&1) of unit tid + (m>>1);
                // tap index: colA = m-1 (valid m<=11), colB = m-2 (valid m>=2).
                v4f w7[7];
                #pragma unroll
                for (int i = 0; i < 7; ++i) w7[i] = tile4[s][tid + i];
                v2f h01A = (v2f){0.f, 0.f}, h23A = h01A, h01B = h01A, h23B = h01A;
                float h4A = 0.f, h4B = 0.f;
                #pragma unroll
                for (int m = 1; m <= 12; ++m) {
                    v2f t = (m & 1) ? (v2f){w7[m >> 1].z, w7[m >> 1].w}
                                    : (v2f){w7[m >> 1].x, w7[m >> 1].y};
                    if (m <= 11) {
                        v2f tw = wp[m - 1] * t;                            // pk_mul
                        h01A += tw;                                        // pk_add
                        h23A = __builtin_elementwise_fma(tw, t, h23A);     // pk_fma
                        h4A = fmaf(tw[0], t[1], h4A);
                    }
                    if (m >= 2) {
                        v2f tw = wp[m - 2] * t;
                        h01B += tw;
                        h23B = __builtin_elementwise_fma(tw, t, h23B);
                        h4B = fmaf(tw[0], t[1], h4B);
                    }
                }
                hist01A[s] = h01A; hist01B[s] = h01B;
                hist23A[s] = h23A; hist23B[s] = h23B;
                hist4[s] = (v2f){h4A, h4B};

                // --- output row (11c + s - 10) completes now ---
                if (c > 0 || s == 10) {
                    v2f a01A = (v2f){0.f, 0.f}, a01B = a01A, a23A = a01A, a23B = a01A, a4 = a01A;
                    #pragma unroll
                    for (int j = 0; j < 11; ++j) {
                        const int sl = (s + 1 + j) % 11;   // static per (s,j)
                        a01A = __builtin_elementwise_fma(wp[j], hist01A[sl], a01A);
                        a01B = __builtin_elementwise_fma(wp[j], hist01B[sl], a01B);
                        a23A = __builtin_elementwise_fma(wp[j], hist23A[sl], a23A);
                        a23B = __builtin_elementwise_fma(wp[j], hist23B[sl], a23B);
                        a4   = __builtin_elementwise_fma(wp[j], hist4[sl],  a4);
                    }
                    lsum += ssim1(a01A, a23A, a4[0]) + ssim1(a01B, a23B, a4[1]);
                }
            }
        }

        __syncthreads();                    // everyone done reading tile
        if (c < NCHUNK - 1) { store_chunk(); __syncthreads(); }
    }

    // ---- reduction: wave shuffle -> LDS -> block partial -> fp64 atomic ----
    #pragma unroll
    for (int off = 32; off > 0; off >>= 1)
        lsum += __shfl_down(lsum, off, 64);
    if ((tid & 63) == 0) wavesum[tid >> 6] = lsum;
    __syncthreads();
    if (tid == 0) {
        float bs = wavesum[0] + wavesum[1] + wavesum[2] + wavesum[3];
        atomicAdd(acc_ws, (double)bs);
        __threadfence();
        unsigned long long old = atomicAdd(ctr, 1ull);
        if (old == (unsigned long long)(NBLOCKS - 1)) {
            __threadfence();
            double total = atomicAdd(acc_ws, 0.0);   // atomic RMW sees all prior adds
            out[0] = (float)(1.0 - total / NPIX);
        }
    }
}

extern "C" void kernel_launch(void* const* d_in, const int* in_sizes, int n_in,
                              void* d_out, int out_size, void* d_ws, size_t ws_size,
                              hipStream_t stream) {
    const float* x = (const float*)d_in[0];   // heatmap_clean
    const float* y = (const float*)d_in[1];   // heatmap_adv
    float* out = (float*)d_out;
    double* acc = (double*)d_ws;
    unsigned long long* ctr = (unsigned long long*)((char*)d_ws + 8);

    // zero the 16B of accumulator+counter state (capture-safe async memset)
    hipMemsetAsync(d_ws, 0, 16, stream);

    GaussW gw;
    double g[11], s = 0.0;
    for (int i = 0; i < 11; ++i) { double d = i - 5; g[i] = exp(-(d * d) / 4.5); s += g[i]; }
    for (int i = 0; i < 11; ++i) gw.w[i] = (float)(g[i] / s);

    dim3 grid(IMG / BROWS, 32);   // (16, 32) = 512 blocks = 2 per CU
    ssim_stream_kernel<<<grid, 256, 0, stream>>>(x, y, acc, ctr, out, gw);
}

// Round 14
// 121.321 us; speedup vs baseline: 1.3633x; 1.0180x over previous
//
#include <hip/hip_runtime.h>
#include <cmath>

// SSIM stability loss: 1 - mean(SSIM(x,y)), 11x11 Gaussian (sigma=1.5), zero SAME
// padding, fp32, 32 x 1 x 512 x 512.
//
// R11 config (best: 47 us): 256 threads = 256 cols x 64-row band, 74 H-rows
// streamed through an 11-row LDS chunk of v4f (x0,y0,x1,y1) units; 11-tap
// window read as 6 ALIGNED ds_read_b128, lane alignment parity folded into a
// 12-tap weight vector; packed v2f builtins; 11-deep circular register
// history for the vertical conv; 512 blocks = 2/CU (proven sweet spot);
// single dispatch, fp64 atomic finish.
//
// R13 -> R14: budget shows ~1 cyc/px unexplained; at ~1.2 effective
// waves/SIMD the only fit is EXPOSED ds_read latency at the top of each
// H-row (6 b128 issued serially before that row's VALU). This round
// software-pipelines the window reads one row ahead (w6cur/w6next), so row
// s+1's read latency overlaps row s's compute within the wave. VGPR ~+24.

#define IMG   512
#define BROWS 64
#define NHROW (BROWS + 10)   // 74 H-rows per band
#define NCHUNK 7             // ceil(74/11)
#define CHR   11             // rows per LDS chunk (== history depth)
#define LCOLS 272            // staged cols per row (covers c0-8 .. c0+263)
#define LUNITS 68            // float4 units per staged row
#define NUNITS (CHR * LUNITS)   // 748
#define NBLOCKS 512
#define NPIX  8388608.0

typedef float v2f __attribute__((ext_vector_type(2)));
typedef float v4f __attribute__((ext_vector_type(4)));

struct GaussW { float w[11]; };

__global__ __launch_bounds__(256)
void ssim_stream_kernel(const float* __restrict__ x, const float* __restrict__ y,
                        double* __restrict__ acc_ws, unsigned long long* __restrict__ ctr,
                        float* __restrict__ out, GaussW gw) {
    // tile4[s][u] = LDS cols (2u, 2u+1) packed as (x0, y0, x1, y1); 16-B units
    __shared__ v4f tile4[CHR][LCOLS / 2];   // 11 * 136 * 16 = 23936 B
    __shared__ float wavesum[4];

    const int tid = threadIdx.x;
    const int c0 = blockIdx.x * 256;
    const int r0 = blockIdx.y * BROWS;
    const size_t img_off = (size_t)blockIdx.z * (IMG * IMG);
    const float* __restrict__ xb = x + img_off;
    const float* __restrict__ yb = y + img_off;

    const int ci = tid;                 // output column; taps at LDS cols ci+3..ci+13
    const int ub = (ci + 3) >> 1;       // v4f unit of aligned window base
    const int p  = (ci + 3) & 1;        // parity: tap k sits at window pos p+k

    // 12-tap per-lane weight vector: window pos m covers LDS col 2*ub + m;
    // logical tap k = m - p, so wv2[m] = w[m-p] (0 outside [0,10]).
    v2f wv2[12];
    #pragma unroll
    for (int m = 0; m < 12; ++m) {
        float lo = (m <= 10) ? gw.w[m] : 0.f;       // p == 0
        float hi = (m >= 1) ? gw.w[m - 1] : 0.f;    // p == 1
        float wm = p ? hi : lo;
        wv2[m][0] = wm; wv2[m][1] = wm;
    }
    v2f wp[11];                          // vertical weights (parity-free)
    #pragma unroll
    for (int k = 0; k < 11; ++k) { wp[k][0] = gw.w[k]; wp[k][1] = gw.w[k]; }

    float4 sxr[3], syr[3];   // staged regs for next chunk (3 iters x 256 thr >= 748)

    auto load_chunk = [&](int c) {
        #pragma unroll
        for (int it = 0; it < 3; ++it) {
            int idx = tid + it * 256;
            int row = idx / LUNITS;
            int u   = idx - row * LUNITS;
            int gr = r0 - 5 + c * CHR + row;       // global image row
            int gc = c0 - 8 + u * 4;               // global col of float4 (16B aligned)
            float4 vx = make_float4(0.f, 0.f, 0.f, 0.f);
            float4 vy = vx;
            if (idx < NUNITS && (unsigned)gr < IMG && (unsigned)gc < IMG) {
                const float* px = xb + (size_t)gr * IMG + gc;
                const float* py = yb + (size_t)gr * IMG + gc;
                vx = *(const float4*)px;
                vy = *(const float4*)py;
            }
            sxr[it] = vx; syr[it] = vy;
        }
    };
    auto store_chunk = [&]() {
        #pragma unroll
        for (int it = 0; it < 3; ++it) {
            int idx = tid + it * 256;
            if (idx < NUNITS) {
                int row = idx / LUNITS;
                int u   = idx - row * LUNITS;
                tile4[row][u * 2]     = (v4f){sxr[it].x, syr[it].x, sxr[it].y, syr[it].y};
                tile4[row][u * 2 + 1] = (v4f){sxr[it].z, syr[it].z, sxr[it].w, syr[it].w};
            }
        }
    };

    v2f hist01[11];    // (hx, hy)
    v2f hist23[11];    // (hxx, hyy)
    float hist4[11];   // hxy
    float lsum = 0.f;
    const float C1 = 1e-4f, C2 = 9e-4f;

    load_chunk(0);
    store_chunk();
    __syncthreads();

    #pragma unroll 1
    for (int c = 0; c < NCHUNK; ++c) {      // 7 chunks x 11 rows = 77 >= 74
        if (c < NCHUNK - 1) load_chunk(c + 1);  // global loads overlap chunk-c compute

        // software pipeline: window reads for row s+1 issued before computing
        // row s, so their ~150-cyc LDS latency hides under row s's VALU.
        v4f w6cur[6], w6next[6];
        #pragma unroll
        for (int i = 0; i < 6; ++i) w6cur[i] = tile4[0][ub + i];

        #pragma unroll
        for (int s = 0; s < CHR; ++s) {     // H-row m = 11c + s; hist slot = s
            if (!(c == NCHUNK - 1 && s >= 8)) {   // m < 74 (wave-uniform guard)
                if (s < CHR - 1) {
                    #pragma unroll
                    for (int i = 0; i < 6; ++i) w6next[i] = tile4[s + 1][ub + i];
                }
                // --- horizontal conv: 12 taps from prefetched w6cur ---
                v2f h01 = (v2f){0.f, 0.f};
                v2f h23 = (v2f){0.f, 0.f};
                float h4 = 0.f;
                #pragma unroll
                for (int m = 0; m < 12; ++m) {
                    v2f t = (m & 1) ? w6cur[m >> 1].zw : w6cur[m >> 1].xy;
                    v2f tw = wv2[m] * t;                          // v_pk_mul_f32
                    h01 += tw;                                    // v_pk_add_f32
                    h23 = __builtin_elementwise_fma(tw, t, h23);  // v_pk_fma_f32
                    h4 = fmaf(tw[0], t[1], h4);                   // w*x*y (scalar)
                }
                hist01[s] = h01; hist23[s] = h23; hist4[s] = h4;

                // --- output row (11c + s - 10) completes now ---
                if (c > 0 || s == 10) {
                    v2f a01 = (v2f){0.f, 0.f};
                    v2f a23 = (v2f){0.f, 0.f};
                    float a4 = 0.f;
                    #pragma unroll
                    for (int j = 0; j < 11; ++j) {
                        const int sl = (s + 1 + j) % 11;   // static per (s,j)
                        a01 = __builtin_elementwise_fma(wp[j], hist01[sl], a01);
                        a23 = __builtin_elementwise_fma(wp[j], hist23[sl], a23);
                        a4 = fmaf(wp[j][0], hist4[sl], a4);
                    }
                    float mx = a01[0], my = a01[1];
                    float mxx = mx * mx, myy = my * my, mxy = mx * my;
                    float sxx = a23[0] - mxx, syy = a23[1] - myy, sxy = a4 - mxy;
                    float num = (2.f * mxy + C1) * (2.f * sxy + C2);
                    float den = (mxx + myy + C1) * (sxx + syy + C2);
                    lsum += num * __builtin_amdgcn_rcpf(den);
                }
                #pragma unroll
                for (int i = 0; i < 6; ++i) w6cur[i] = w6next[i];
            }
        }

        __syncthreads();                    // everyone done reading tile
        if (c < NCHUNK - 1) { store_chunk(); __syncthreads(); }
    }

    // ---- reduction: wave shuffle -> LDS -> block partial -> fp64 atomic ----
    #pragma unroll
    for (int off = 32; off > 0; off >>= 1)
        lsum += __shfl_down(lsum, off, 64);
    if ((tid & 63) == 0) wavesum[tid >> 6] = lsum;
    __syncthreads();
    if (tid == 0) {
        float bs = wavesum[0] + wavesum[1] + wavesum[2] + wavesum[3];
        atomicAdd(acc_ws, (double)bs);
        __threadfence();
        unsigned long long old = atomicAdd(ctr, 1ull);
        if (old == (unsigned long long)(NBLOCKS - 1)) {
            __threadfence();
            double total = atomicAdd(acc_ws, 0.0);   // atomic RMW sees all prior adds
            out[0] = (float)(1.0 - total / NPIX);
        }
    }
}

extern "C" void kernel_launch(void* const* d_in, const int* in_sizes, int n_in,
                              void* d_out, int out_size, void* d_ws, size_t ws_size,
                              hipStream_t stream) {
    const float* x = (const float*)d_in[0];   // heatmap_clean
    const float* y = (const float*)d_in[1];   // heatmap_adv
    float* out = (float*)d_out;
    double* acc = (double*)d_ws;
    unsigned long long* ctr = (unsigned long long*)((char*)d_ws + 8);

    // zero the 16B of accumulator+counter state (capture-safe async memset)
    hipMemsetAsync(d_ws, 0, 16, stream);

    GaussW gw;
    double g[11], s = 0.0;
    for (int i = 0; i < 11; ++i) { double d = i - 5; g[i] = exp(-(d * d) / 4.5); s += g[i]; }
    for (int i = 0; i < 11; ++i) gw.w[i] = (float)(g[i] / s);

    dim3 grid(2, IMG / BROWS, 32);   // (2, 8, 32) = 512 blocks = 2 per CU
    ssim_stream_kernel<<<grid, 256, 0, stream>>>(x, y, acc, ctr, out, gw);
}